// Round 8
// baseline (119.097 us; speedup 1.0000x reference)
//
#include <hip/hip_runtime.h>

// CostConcatenation: out[b,d,h,w, 0:16] = left[b,h,w,:]        (if valid else 0)
//                    out[b,d,h,w,16:32] = right[b,h,w-disp,:]  (if valid else 0)
// disp = d - 112 ; idx = w + (112 - d) ; valid = 0<=idx<W
// Output (B, D, H, W, 2C) fp32 = 604 MB -> write-BW bound.
// History: R1 plain 129us. R3 nt stores 118us. R4 d-tile neutral (reads hidden).
// R5 sc0/sc1 breaks harness coherence. R6 XCD h-stripe -6% (write scatter hurts).
// R7 persistent linear sweep 115.9us (5.2 TB/s; fill comparator 6.76 TB/s).
// R8: branchless. The guarded load can't be hoisted above the exec-mask branch,
// chaining each store's vmcnt behind a late branchy load. Replace with
// clamped-address unconditional load (always in-bounds, cache-served) +
// cndmask zeroing -> scheduler can pipeline loads arbitrarily deep.

constexpr int B_ = 2;
constexpr int H_ = 96;
constexpr int W_ = 192;
constexpr int D_ = 128;

typedef float v4f __attribute__((ext_vector_type(4)));

constexpr unsigned TOTAL4   = 37748736u;      // B*D*H*W*8 float4 elements (604 MB)
constexpr unsigned NBLK     = 2048u;          // 8 blocks/CU * 256 CU
constexpr unsigned NTHREADS = NBLK * 256u;    // 524288
constexpr int      ITERS    = TOTAL4 / NTHREADS;  // 72 exactly

__global__ __launch_bounds__(256) void cost_concat_kernel(
    const v4f* __restrict__ left,
    const v4f* __restrict__ right,
    v4f* __restrict__ out)
{
    unsigned j = blockIdx.x * 256u + threadIdx.x;

    #pragma unroll 4
    for (int it = 0; it < ITERS; ++it, j += NTHREADS) {
        // decode flat float4 index -> (rowid, w, c4); rowid = (b*128+d)*96+h
        const unsigned rowid = j / 1536u;            // magic mul
        const unsigned rr    = j - rowid * 1536u;
        const unsigned w     = rr >> 3;
        const unsigned c4    = rr & 7u;              // grid-stride-invariant
        const unsigned b     = rowid / 12288u;       // 128*96
        const unsigned t     = rowid - b * 12288u;
        const unsigned d     = t / 96u;              // magic mul
        const unsigned h     = t - d * 96u;

        const int idx   = (int)w + 112 - (int)d;     // right-image column
        const bool valid = (unsigned)idx < (unsigned)W_;
        const int idxc  = idx < 0 ? 0 : (idx > W_ - 1 ? W_ - 1 : idx);  // med3
        const unsigned rowBase = (b * H_ + h) * (W_ * 4);  // input row, float4

        // Branch-free source address: always in-bounds, cache-served.
        const v4f* src = (c4 < 4u)
            ? (left  + rowBase + w * 4u + c4)
            : (right + rowBase + (unsigned)idxc * 4u + (c4 - 4u));
        v4f v = *src;                                 // unconditional load
        if (!valid) v = (v4f)(0.f);                   // 4x cndmask

        __builtin_nontemporal_store(v, out + j);
    }
}

extern "C" void kernel_launch(void* const* d_in, const int* in_sizes, int n_in,
                              void* d_out, int out_size, void* d_ws, size_t ws_size,
                              hipStream_t stream)
{
    const v4f* left  = (const v4f*)d_in[0];
    const v4f* right = (const v4f*)d_in[1];
    v4f* out = (v4f*)d_out;

    cost_concat_kernel<<<dim3(NBLK), 256, 0, stream>>>(left, right, out);
}